// Round 2
// baseline (201.857 us; speedup 1.0000x reference)
//
#include <hip/hip_runtime.h>
#include <math.h>

#define THREADS 256
#define WAVES (THREADS / 64)

// One block per row. Single pass over the row:
//  - online logsumexp (running max m, running sum s = sum exp(x - m))
//  - fused windowed raw-x sum (window [t0, t1] inclusive, <=64 elems)
// per_sample = (m + log s) - wsum/count ; out = mean over rows via atomicAdd.
__global__ __launch_bounds__(THREADS)
void ce_loss_kernel(const float* __restrict__ x,
                    const int* __restrict__ targets,
                    const int* __restrict__ positives,
                    float* __restrict__ out,
                    int N, float invB)
{
    const int b = blockIdx.x;
    const float4* row4 = reinterpret_cast<const float4*>(x + (size_t)b * N);
    const int t0 = targets[b];
    const int t1 = t0 + positives[b];   // inclusive end
    const int n4 = N >> 2;

    float m = -INFINITY;
    float s = 0.0f;
    float wsum = 0.0f;

    for (int i = threadIdx.x; i < n4; i += THREADS) {
        float4 v = row4[i];
        const int j = i << 2;

        // online logsumexp update
        float vm = fmaxf(fmaxf(v.x, v.y), fmaxf(v.z, v.w));
        if (vm > m) { s *= __expf(m - vm); m = vm; }
        s += __expf(v.x - m);
        s += __expf(v.y - m);
        s += __expf(v.z - m);
        s += __expf(v.w - m);

        // fused window sum (branchless selects; window is tiny)
        wsum += (j     >= t0 && j     <= t1) ? v.x : 0.0f;
        wsum += (j + 1 >= t0 && j + 1 <= t1) ? v.y : 0.0f;
        wsum += (j + 2 >= t0 && j + 2 <= t1) ? v.z : 0.0f;
        wsum += (j + 3 >= t0 && j + 3 <= t1) ? v.w : 0.0f;
    }

    // 64-lane butterfly reduction with logsumexp merge
    #pragma unroll
    for (int off = 32; off > 0; off >>= 1) {
        float om = __shfl_xor(m, off, 64);
        float os = __shfl_xor(s, off, 64);
        float ow = __shfl_xor(wsum, off, 64);
        float nm = fmaxf(m, om);
        s = s * __expf(m - nm) + os * __expf(om - nm);
        m = nm;
        wsum += ow;
    }

    // cross-wave combine via LDS (4 waves)
    __shared__ float sm[WAVES], ss[WAVES], sw[WAVES];
    const int wave = threadIdx.x >> 6;
    const int lane = threadIdx.x & 63;
    if (lane == 0) { sm[wave] = m; ss[wave] = s; sw[wave] = wsum; }
    __syncthreads();

    if (threadIdx.x == 0) {
        m = sm[0]; s = ss[0]; wsum = sw[0];
        #pragma unroll
        for (int w = 1; w < WAVES; ++w) {
            float om = sm[w], os = ss[w];
            float nm = fmaxf(m, om);
            s = s * __expf(m - nm) + os * __expf(om - nm);
            m = nm;
            wsum += sw[w];
        }
        const float count = (float)(t1 - t0 + 1);
        const float per_sample = (m + logf(s)) - wsum / count;
        atomicAdd(out, per_sample * invB);
    }
}

extern "C" void kernel_launch(void* const* d_in, const int* in_sizes, int n_in,
                              void* d_out, int out_size, void* d_ws, size_t ws_size,
                              hipStream_t stream) {
    const float* inputs    = (const float*)d_in[0];
    const int*   targets   = (const int*)d_in[1];
    const int*   positives = (const int*)d_in[2];
    float* out = (float*)d_out;

    const int B = in_sizes[1];          // 1024
    const int N = in_sizes[0] / B;      // 32768

    // d_out is re-poisoned to 0xAA before every timed launch — zero it.
    hipMemsetAsync(d_out, 0, sizeof(float), stream);

    ce_loss_kernel<<<B, THREADS, 0, stream>>>(inputs, targets, positives, out,
                                              N, 1.0f / (float)B);
}

// Round 3
// 196.121 us; speedup vs baseline: 1.0292x; 1.0292x over previous
//
#include <hip/hip_runtime.h>
#include <math.h>

#define THREADS 512
#define WAVES (THREADS / 64)

// Branchless online-logsumexp update of chain k with value v.
#define LSE_UPD(mk, sk, v)                                    \
    {                                                         \
        float nm_ = fmaxf((mk), (v));                         \
        (sk) = (sk) * __expf((mk) - nm_) + __expf((v) - nm_); \
        (mk) = nm_;                                           \
    }

// Merge chain (mb,sb) into (ma,sa).
#define LSE_MERGE(ma, sa, mb, sb)                                  \
    {                                                              \
        float nm_ = fmaxf((ma), (mb));                             \
        (sa) = (sa) * __expf((ma) - nm_) + (sb) * __expf((mb) - nm_); \
        (ma) = nm_;                                                \
    }

// One block per row, single pass. 8 independent online-LSE chains
// (2 float4 loads per iter x 4 components) for ILP; fused window sum.
// Writes per_sample[b] to row_out.
__global__ __launch_bounds__(THREADS)
void ce_row_kernel(const float* __restrict__ x,
                   const int* __restrict__ targets,
                   const int* __restrict__ positives,
                   float* __restrict__ row_out,
                   int N)
{
    const int b = blockIdx.x;
    const float4* row4 = reinterpret_cast<const float4*>(x + (size_t)b * N);
    const int t0 = targets[b];
    const unsigned wlen = (unsigned)positives[b];   // window length - 1 (>= 0)
    const int n4 = N >> 2;

    float m0 = -INFINITY, m1 = -INFINITY, m2 = -INFINITY, m3 = -INFINITY;
    float m4 = -INFINITY, m5 = -INFINITY, m6 = -INFINITY, m7 = -INFINITY;
    float s0 = 0.f, s1 = 0.f, s2 = 0.f, s3 = 0.f;
    float s4 = 0.f, s5 = 0.f, s6 = 0.f, s7 = 0.f;
    float wsum = 0.f;

    int i = threadIdx.x;
    for (; i + THREADS < n4; i += 2 * THREADS) {
        float4 a = row4[i];
        float4 c = row4[i + THREADS];
        const int ja = i << 2;
        const int jc = (i + THREADS) << 2;

        LSE_UPD(m0, s0, a.x); LSE_UPD(m1, s1, a.y);
        LSE_UPD(m2, s2, a.z); LSE_UPD(m3, s3, a.w);
        LSE_UPD(m4, s4, c.x); LSE_UPD(m5, s5, c.y);
        LSE_UPD(m6, s6, c.z); LSE_UPD(m7, s7, c.w);

        wsum += ((unsigned)(ja     - t0) <= wlen) ? a.x : 0.f;
        wsum += ((unsigned)(ja + 1 - t0) <= wlen) ? a.y : 0.f;
        wsum += ((unsigned)(ja + 2 - t0) <= wlen) ? a.z : 0.f;
        wsum += ((unsigned)(ja + 3 - t0) <= wlen) ? a.w : 0.f;
        wsum += ((unsigned)(jc     - t0) <= wlen) ? c.x : 0.f;
        wsum += ((unsigned)(jc + 1 - t0) <= wlen) ? c.y : 0.f;
        wsum += ((unsigned)(jc + 2 - t0) <= wlen) ? c.z : 0.f;
        wsum += ((unsigned)(jc + 3 - t0) <= wlen) ? c.w : 0.f;
    }
    if (i < n4) {  // tail (not taken for N=32768, THREADS=512)
        float4 a = row4[i];
        const int ja = i << 2;
        LSE_UPD(m0, s0, a.x); LSE_UPD(m1, s1, a.y);
        LSE_UPD(m2, s2, a.z); LSE_UPD(m3, s3, a.w);
        wsum += ((unsigned)(ja     - t0) <= wlen) ? a.x : 0.f;
        wsum += ((unsigned)(ja + 1 - t0) <= wlen) ? a.y : 0.f;
        wsum += ((unsigned)(ja + 2 - t0) <= wlen) ? a.z : 0.f;
        wsum += ((unsigned)(ja + 3 - t0) <= wlen) ? a.w : 0.f;
    }

    // Merge the 8 chains into (m0, s0).
    LSE_MERGE(m0, s0, m1, s1); LSE_MERGE(m2, s2, m3, s3);
    LSE_MERGE(m4, s4, m5, s5); LSE_MERGE(m6, s6, m7, s7);
    LSE_MERGE(m0, s0, m2, s2); LSE_MERGE(m4, s4, m6, s6);
    LSE_MERGE(m0, s0, m4, s4);

    // 64-lane butterfly reduction.
    #pragma unroll
    for (int off = 32; off > 0; off >>= 1) {
        float om = __shfl_xor(m0, off, 64);
        float os = __shfl_xor(s0, off, 64);
        float ow = __shfl_xor(wsum, off, 64);
        LSE_MERGE(m0, s0, om, os);
        wsum += ow;
    }

    // Cross-wave combine via LDS.
    __shared__ float sm[WAVES], ss[WAVES], sw[WAVES];
    const int wave = threadIdx.x >> 6;
    const int lane = threadIdx.x & 63;
    if (lane == 0) { sm[wave] = m0; ss[wave] = s0; sw[wave] = wsum; }
    __syncthreads();

    if (threadIdx.x == 0) {
        m0 = sm[0]; s0 = ss[0]; wsum = sw[0];
        #pragma unroll
        for (int w = 1; w < WAVES; ++w) {
            LSE_MERGE(m0, s0, sm[w], ss[w]);
            wsum += sw[w];
        }
        const float count = (float)(wlen + 1u);
        row_out[b] = (m0 + logf(s0)) - wsum / count;
    }
}

// Mean over B per-row values -> out[0].
__global__ __launch_bounds__(256)
void ce_reduce_kernel(const float* __restrict__ row_vals,
                      float* __restrict__ out, int B, float invB)
{
    float acc = 0.f;
    for (int i = threadIdx.x; i < B; i += 256) acc += row_vals[i];
    #pragma unroll
    for (int off = 32; off > 0; off >>= 1) acc += __shfl_xor(acc, off, 64);

    __shared__ float sb[4];
    const int wave = threadIdx.x >> 6;
    const int lane = threadIdx.x & 63;
    if (lane == 0) sb[wave] = acc;
    __syncthreads();
    if (threadIdx.x == 0)
        out[0] = (sb[0] + sb[1] + sb[2] + sb[3]) * invB;
}

extern "C" void kernel_launch(void* const* d_in, const int* in_sizes, int n_in,
                              void* d_out, int out_size, void* d_ws, size_t ws_size,
                              hipStream_t stream) {
    const float* inputs    = (const float*)d_in[0];
    const int*   targets   = (const int*)d_in[1];
    const int*   positives = (const int*)d_in[2];
    float* out = (float*)d_out;
    float* row_vals = (float*)d_ws;     // B floats of scratch

    const int B = in_sizes[1];          // 1024
    const int N = in_sizes[0] / B;      // 32768

    ce_row_kernel<<<B, THREADS, 0, stream>>>(inputs, targets, positives,
                                             row_vals, N);
    ce_reduce_kernel<<<1, 256, 0, stream>>>(row_vals, out, B, 1.0f / (float)B);
}